// Round 15
// baseline (195.905 us; speedup 1.0000x reference)
//
#include <hip/hip_runtime.h>
#include <hip/hip_bf16.h>
#include <math.h>

#define B_ 2
#define N_ 768
#define T_ 96
#define FM_ 8
#define HID_ 64
#define TD_ 32
#define MD_ 32
#define TILE 16
#define TI32 32
#define NTILES (N_/TILE)            // 48
#define PERB 600                    // sum_{a=0}^{23} (48-2a)
#define NTOT (B_*PERB)              // 1200
#define NORMB 384                   // last 384 blocks also do normalization

typedef __attribute__((ext_vector_type(8))) _Float16 half8v;
typedef __attribute__((ext_vector_type(2))) _Float16 half2v;
typedef __attribute__((ext_vector_type(4))) float f32x4;
typedef __attribute__((ext_vector_type(4))) unsigned int uint4v;

__device__ __forceinline__ unsigned int pkrtz(float a, float b){
  auto t = __builtin_amdgcn_cvt_pkrtz(a, b);
  unsigned int u;
  __builtin_memcpy(&u, &t, 4);
  return u;
}
__device__ __forceinline__ half2v u2h(unsigned int u){
  return __builtin_bit_cast(half2v, u);
}

__device__ __forceinline__ float ftanh(float x){
  float e = __expf(2.f * x);
  return 1.f - 2.f * __builtin_amdgcn_rcpf(e + 1.f);
}

__device__ __forceinline__ float wave_sum64(float v){
  #pragma unroll
  for (int m = 32; m; m >>= 1) v += __shfl_xor(v, m);
  return v;
}
__device__ __forceinline__ float wave_max64(float v){
  #pragma unroll
  for (int m = 32; m; m >>= 1) v = fmaxf(v, __shfl_xor(v, m));
  return v;
}

// ---------------------------------------------------------------------------
// Kernel 1: per-(b,n) features -> hf (f16), s_i, s_j. 4 rows/block (4 waves).
// Blocks [384, 386): pack W_d into f16 fragments, q=(blk-384)*4+wave.
// ---------------------------------------------------------------------------
__global__ __launch_bounds__(256) void feat_kernel(
    const float* __restrict__ x_hist, const float* __restrict__ x_mark,
    const float* __restrict__ te_w1, const float* __restrict__ te_b1,
    const float* __restrict__ te_w2, const float* __restrict__ te_b2,
    const float* __restrict__ me_w1, const float* __restrict__ me_b1,
    const float* __restrict__ me_w2, const float* __restrict__ me_b2,
    const float* __restrict__ nf_w,  const float* __restrict__ nf_b,
    const float* __restrict__ ps_w1,
    _Float16* __restrict__ hf, float* __restrict__ si_out, float* __restrict__ sj_out,
    _Float16* __restrict__ wdf)
{
  const int tid  = threadIdx.x;
  const int lane = tid & 63;
  const int w    = tid >> 6;
  const int NB   = (B_ * N_) / 4;       // 384

  if (blockIdx.x >= NB) {               // W_d packing blocks
    const int q  = (blockIdx.x - NB) * 4 + w;   // 0..7 = nt*2+s
    const int nt = q >> 1, s = q & 1;
    const int col = (lane & 15) + 16 * nt;
    const int k0  = s * 32 + ((lane >> 4) << 3);
    #pragma unroll
    for (int jj = 0; jj < 8; ++jj) {
      float v = ps_w1[(2 * HID_ + k0 + jj) * HID_ + col];
      wdf[(q * 64 + lane) * 8 + jj] = (_Float16)v;
    }
    return;
  }

  const int row = blockIdx.x * 4 + w;   // b*N + n

  __shared__ float st [4][3];
  __shared__ float ms [4][FM_];
  __shared__ float t1s[4][TD_];
  __shared__ float m1s[4][MD_];
  __shared__ float hc [4][HID_];
  __shared__ float hs [4][HID_];

  const float* xh = x_hist + (long)row * T_;
  float s  = xh[lane];
  float mx = s;
  if (lane < T_ - 64) { float v = xh[lane + 64]; s += v; mx = fmaxf(mx, v); }
  s  = wave_sum64(s);
  mx = wave_max64(mx);
  if (lane == 0) { st[w][0] = xh[T_ - 1]; st[w][1] = s * (1.0f / T_); st[w][2] = mx; }

  const float* xm = x_mark + (long)row * T_ * FM_;
  float msv = 0.f;
  #pragma unroll
  for (int k = 0; k < 12; ++k) msv += xm[lane + 64 * k];
  msv += __shfl_xor(msv, 8);
  msv += __shfl_xor(msv, 16);
  msv += __shfl_xor(msv, 32);
  if (lane < FM_) ms[w][lane] = msv * (1.0f / T_);
  __syncthreads();

  if (lane < TD_) {
    float a = te_b1[lane];
    #pragma unroll
    for (int k = 0; k < 3; ++k) a += st[w][k] * te_w1[k * TD_ + lane];
    t1s[w][lane] = fmaxf(a, 0.f);
    float am = me_b1[lane];
    #pragma unroll
    for (int k = 0; k < FM_; ++k) am += ms[w][k] * me_w1[k * MD_ + lane];
    m1s[w][lane] = fmaxf(am, 0.f);
  }
  __syncthreads();
  if (lane < TD_) {
    float a = te_b2[lane];
    #pragma unroll
    for (int k = 0; k < TD_; ++k) a += t1s[w][k] * te_w2[k * TD_ + lane];
    hc[w][lane] = a;
    float am = me_b2[lane];
    #pragma unroll
    for (int k = 0; k < MD_; ++k) am += m1s[w][k] * me_w2[k * MD_ + lane];
    hc[w][TD_ + lane] = am;
  }
  __syncthreads();
  {
    float a = nf_b[lane];
    #pragma unroll
    for (int k = 0; k < HID_; ++k) a += hc[w][k] * nf_w[k * HID_ + lane];
    float hv = fmaxf(a, 0.f);
    hs[w][lane] = hv;
    hf[(long)row * HID_ + lane] = (_Float16)hv;
  }
  __syncthreads();
  {
    float a1 = 0.f, a2 = 0.f;
    #pragma unroll
    for (int k = 0; k < HID_; ++k) {
      float hv = hs[w][k];
      a1 += hv * ps_w1[k * HID_ + lane];
      a2 += hv * ps_w1[(HID_ + k) * HID_ + lane];
    }
    si_out[(long)row * HID_ + lane] = a1;
    sj_out[(long)row * HID_ + lane] = a2;
  }
}

// ---------------------------------------------------------------------------
// Kernel 2: pairwise delta via transposed f16 MFMA + FUSED normalization.
// Block = 32 i-rows x 16 j-rows, 8 waves (512 thr); wave w owns i-rows
// 4w..4w+3. After delta writes: release-add to 8 striped counters; the
// last-dispatched NORMB blocks spin for all 1200, then each normalizes 4
// rows of out. Deadlock-free: every block adds before any block waits.
// ---------------------------------------------------------------------------
__global__ __launch_bounds__(512) void pair_kernel(
    const _Float16* __restrict__ hf, const float* __restrict__ si, const float* __restrict__ sj,
    const float* __restrict__ ps_b1, const float* __restrict__ ps_w2,
    const float* __restrict__ ps_b2, const _Float16* __restrict__ wdf,
    const float* __restrict__ a_static, const float* __restrict__ raw_lambda,
    unsigned int* __restrict__ ctr,
    float* __restrict__ delta)
{
  int bidx = blockIdx.x;
  int b = bidx / PERB;
  int t = bidx % PERB;
  int a = 0;
  while (t >= NTILES - 2 * a) { t -= NTILES - 2 * a; ++a; }
  int tJ = 2 * a + t;
  const int i0 = a * TI32, j0 = tJ * TILE;

  __shared__ _Float16 hI[TI32][HID_];      // 4 KB (uniform-row reads)
  __shared__ _Float16 hJ[TILE][72];        // 2.25 KB (padded rows)
  __shared__ unsigned int PI[TI32][HID_];  // 8 KB  {sII+b1, sJI} f16x2
  __shared__ unsigned int PJ[TILE][68];    // 4.25 KB {sJJ, sIJ+b1} f16x2
  __shared__ unsigned int w2p[HID_];       // 256 B {w2,w2} f16x2
  __shared__ float ps2[8];                 // norm partials

  const int tid  = threadIdx.x;
  const int lane = tid & 63;
  const int w    = tid >> 6;               // 0..7

  // ---- staging (512 threads) ----
  if (tid < 256) {                         // I-side: 32 rows x 8 chunks
    const int r8 = tid >> 3;
    const int c0 = 8 * (tid & 7);
    const f32x4 bA = *(const f32x4*)(ps_b1 + c0);
    const f32x4 bB = *(const f32x4*)(ps_b1 + c0 + 4);
    const long gri = ((long)(b * N_) + i0 + r8) * HID_ + c0;
    *(half8v*)&hI[r8][c0] = *(const half8v*)(hf + gri);
    f32x4 ia = *(const f32x4*)(si + gri), ib = *(const f32x4*)(si + gri + 4);
    f32x4 ja = *(const f32x4*)(sj + gri), jb = *(const f32x4*)(sj + gri + 4);
    uint4v pa, pb;
    #pragma unroll
    for (int q = 0; q < 4; ++q) {
      pa[q] = pkrtz(ia[q] + bA[q], ja[q]);
      pb[q] = pkrtz(ib[q] + bB[q], jb[q]);
    }
    *(uint4v*)&PI[r8][c0] = pa;
    *(uint4v*)&PI[r8][c0 + 4] = pb;
  } else if (tid < 384) {                  // J-side: 16 rows x 8 chunks
    const int t2 = tid - 256;
    const int rj = t2 >> 3;
    const int c0 = 8 * (t2 & 7);
    const f32x4 bA = *(const f32x4*)(ps_b1 + c0);
    const f32x4 bB = *(const f32x4*)(ps_b1 + c0 + 4);
    const long grj = ((long)(b * N_) + j0 + rj) * HID_ + c0;
    *(half8v*)&hJ[rj][c0] = *(const half8v*)(hf + grj);
    f32x4 sja = *(const f32x4*)(sj + grj), sjb = *(const f32x4*)(sj + grj + 4);
    f32x4 sia = *(const f32x4*)(si + grj), sib = *(const f32x4*)(si + grj + 4);
    uint4v qa, qb;
    #pragma unroll
    for (int q = 0; q < 4; ++q) {
      qa[q] = pkrtz(sja[q], sia[q] + bA[q]);
      qb[q] = pkrtz(sjb[q], sib[q] + bB[q]);
    }
    *(uint4v*)&PJ[rj][c0] = qa;
    *(uint4v*)&PJ[rj][c0 + 4] = qb;
  } else if (tid < 400) {                  // w2: 16 threads x 4
    const int t4 = tid - 384;
    f32x4 wv = *(const f32x4*)(ps_w2 + t4 * 4);
    #pragma unroll
    for (int q = 0; q < 4; ++q) w2p[t4 * 4 + q] = pkrtz(wv[q], wv[q]);
  }
  const float b2 = ps_b2[0];
  __syncthreads();

  const int g   = lane >> 4;     // 0..3
  const int c16 = lane & 15;     // = j within tile

  // Wd fragments (A operand), prepacked f16
  half8v wfr[8];
  const half8v* wdp = (const half8v*)wdf;
  #pragma unroll
  for (int q = 0; q < 8; ++q) wfr[q] = wdp[q * 64 + lane];

  // m-invariant hoists
  half8v hj0 = *(const half8v*)&hJ[c16][8 * g];
  half8v hj1 = *(const half8v*)&hJ[c16][32 + 8 * g];
  uint4v pjh[4], w2h[4];
  #pragma unroll
  for (int mt = 0; mt < 4; ++mt) {
    pjh[mt] = *(const uint4v*)&PJ[c16][16 * mt + 4 * g];
    w2h[mt] = *(const uint4v*)&w2p[16 * mt + 4 * g];
  }
  const half2v hz = (half2v){(_Float16)0.f, (_Float16)0.f};

  float* drow = delta + (long)b * N_ * N_;

  #pragma unroll
  for (int m = 0; m < 4; ++m) {
    const int iloc = w * 4 + m;            // 8 waves x 4 rows = 32
    const int i = i0 + iloc;

    // diff = |hi - hj| in f16 (pk_sub + and-mask abs)
    half8v hi0 = *(const half8v*)&hI[iloc][8 * g];
    half8v hi1 = *(const half8v*)&hI[iloc][32 + 8 * g];
    half8v d0 = hi0 - hj0;
    half8v d1 = hi1 - hj1;
    uint4v u0 = __builtin_bit_cast(uint4v, d0) & 0x7FFF7FFFu;
    uint4v u1 = __builtin_bit_cast(uint4v, d1) & 0x7FFF7FFFu;
    half8v af0 = __builtin_bit_cast(half8v, u0);
    half8v af1 = __builtin_bit_cast(half8v, u1);

    f32x4 acc[4];
    #pragma unroll
    for (int mt = 0; mt < 4; ++mt) acc[mt] = (f32x4){0.f, 0.f, 0.f, 0.f};
    #pragma unroll
    for (int mt = 0; mt < 4; ++mt) {
      acc[mt] = __builtin_amdgcn_mfma_f32_16x16x32_f16(wfr[2 * mt + 0], af0, acc[mt], 0, 0, 0);
      acc[mt] = __builtin_amdgcn_mfma_f32_16x16x32_f16(wfr[2 * mt + 1], af1, acc[mt], 0, 0, 0);
    }

    // packed-f16 epilogue, two accumulator chains
    half2v sA = hz, sB = hz;
    #pragma unroll
    for (int mt = 0; mt < 4; ++mt) {
      uint4v pim = *(const uint4v*)&PI[iloc][16 * mt + 4 * g];   // uniform row
      #pragma unroll
      for (int r = 0; r < 4; ++r) {
        half2v pre = u2h(pim[r]) + u2h(pjh[mt][r]);
        auto avt = __builtin_amdgcn_cvt_pkrtz(acc[mt][r], acc[mt][r]);
        half2v av2;
        __builtin_memcpy(&av2, &avt, 4);
        pre = pre + av2;
        pre = __builtin_elementwise_max(pre, hz);
        if (mt & 1) sB = sB + pre * u2h(w2h[mt][r]);
        else        sA = sA + pre * u2h(w2h[mt][r]);
      }
    }
    half2v sP = sA + sB;
    {
      int v0 = __builtin_bit_cast(int, sP);
      int o0 = __shfl_xor(v0, 16);
      sP = sP + __builtin_bit_cast(half2v, o0);
      int v1 = __builtin_bit_cast(int, sP);
      int o1 = __shfl_xor(v1, 32);
      sP = sP + __builtin_bit_cast(half2v, o1);
    }

    if (g == 0) {
      const int j = j0 + c16;
      if (i < j) {
        float a1 = (float)sP[0] + b2;
        float a2 = (float)sP[1] + b2;
        float sym = 0.5f * (ftanh(a1) + ftanh(a2));
        drow[(long)i * N_ + j] = sym;
        drow[(long)j * N_ + i] = sym;
      } else if (i == j) {
        drow[(long)i * N_ + i] = 0.f;
      }
    }
  }

  // ---- completion signal (every block, exactly once) ----
  __syncthreads();                       // all waves' delta stores issued+drained
  if (tid == 0) {
    __threadfence();                     // device-scope release of this block's writes
    __hip_atomic_fetch_add(ctr + (bidx & 7), 1u, __ATOMIC_RELEASE,
                           __HIP_MEMORY_SCOPE_AGENT);
  }

  // ---- fused normalization: last-dispatched NORMB blocks only ----
  if (bidx >= NTOT - NORMB) {
    if (tid == 0) {
      unsigned int sum;
      do {
        __builtin_amdgcn_s_sleep(16);
        sum = 0;
        #pragma unroll
        for (int q = 0; q < 8; ++q)
          sum += __hip_atomic_load(ctr + q, __ATOMIC_ACQUIRE,
                                   __HIP_MEMORY_SCOPE_AGENT);
      } while (sum < (unsigned)NTOT);
      __threadfence();                   // acquire: invalidate stale cache
    }
    __syncthreads();

    const float lam = 1.f / (1.f + expf(-raw_lambda[0]));
    const int k    = bidx - (NTOT - NORMB);
    const int rloc = tid >> 7;           // 0..3 (row within group of 4)
    const int tr   = tid & 127;
    const int row  = k * 4 + rloc;       // 0..1535 = b*N + i
    const int i    = row % N_;
    const float* arow = a_static + (long)i * N_;
    float* nrow = delta + (long)row * N_;

    float vals[6];
    float s = 0.f;
    #pragma unroll
    for (int q = 0; q < 6; ++q) {
      int j = tr + 128 * q;
      float v = arow[j] + lam * nrow[j];
      v = fmaxf(v, 0.f);
      vals[q] = v;
      s += v;
    }
    s = wave_sum64(s);
    if (lane == 0) ps2[w] = s;
    __syncthreads();
    float tot = ps2[2 * rloc] + ps2[2 * rloc + 1];
    float inv = 1.f / fmaxf(tot, 1e-6f);
    #pragma unroll
    for (int q = 0; q < 6; ++q) nrow[tr + 128 * q] = vals[q] * inv;
    if (k == 0 && tid == 0) delta[(long)B_ * N_ * N_] = lam;
  }
}

// ---------------------------------------------------------------------------
extern "C" void kernel_launch(void* const* d_in, const int* in_sizes, int n_in,
                              void* d_out, int out_size, void* d_ws, size_t ws_size,
                              hipStream_t stream) {
  const float* x_hist     = (const float*)d_in[0];
  const float* x_mark     = (const float*)d_in[1];
  const float* a_static   = (const float*)d_in[2];
  const float* te_w1      = (const float*)d_in[3];
  const float* te_b1      = (const float*)d_in[4];
  const float* te_w2      = (const float*)d_in[5];
  const float* te_b2      = (const float*)d_in[6];
  const float* me_w1      = (const float*)d_in[7];
  const float* me_b1      = (const float*)d_in[8];
  const float* me_w2      = (const float*)d_in[9];
  const float* me_b2      = (const float*)d_in[10];
  const float* nf_w       = (const float*)d_in[11];
  const float* nf_b       = (const float*)d_in[12];
  const float* ps_w1      = (const float*)d_in[13];
  const float* ps_b1      = (const float*)d_in[14];
  const float* ps_w2      = (const float*)d_in[15];
  const float* ps_b2      = (const float*)d_in[16];
  const float* raw_lambda = (const float*)d_in[17];

  float* out = (float*)d_out;
  char* ws = (char*)d_ws;
  _Float16* hf = (_Float16*)ws;                          // 196608 B
  float* si    = (float*)(ws + 196608);                  // 393216 B
  float* sj    = (float*)(ws + 196608 + 393216);         // 393216 B
  _Float16* wdf = (_Float16*)(ws + 196608 + 2 * 393216); // 8192 B
  unsigned int* ctr = (unsigned int*)(ws + 196608 + 2 * 393216 + 8192); // 32 B

  hipMemsetAsync((void*)ctr, 0, 8 * sizeof(unsigned int), stream);

  feat_kernel<<<(B_ * N_) / 4 + 2, 256, 0, stream>>>(
      x_hist, x_mark, te_w1, te_b1, te_w2, te_b2,
      me_w1, me_b1, me_w2, me_b2, nf_w, nf_b, ps_w1, hf, si, sj, wdf);

  pair_kernel<<<NTOT, 512, 0, stream>>>(
      hf, si, sj, ps_b1, ps_w2, ps_b2, wdf, a_static, raw_lambda, ctr, out);
}

// Round 16
// 111.366 us; speedup vs baseline: 1.7591x; 1.7591x over previous
//
#include <hip/hip_runtime.h>
#include <hip/hip_bf16.h>
#include <math.h>

#define B_ 2
#define N_ 768
#define T_ 96
#define FM_ 8
#define HID_ 64
#define TD_ 32
#define MD_ 32
#define TILE 16
#define TI32 32
#define NTILES (N_/TILE)            // 48
#define PERB 600                    // sum_{a=0}^{23} (48-2a)

typedef __attribute__((ext_vector_type(8))) _Float16 half8v;
typedef __attribute__((ext_vector_type(2))) _Float16 half2v;
typedef __attribute__((ext_vector_type(4))) float f32x4;
typedef __attribute__((ext_vector_type(4))) unsigned int uint4v;

__device__ __forceinline__ unsigned int pkrtz(float a, float b){
  auto t = __builtin_amdgcn_cvt_pkrtz(a, b);
  unsigned int u;
  __builtin_memcpy(&u, &t, 4);
  return u;
}
__device__ __forceinline__ half2v u2h(unsigned int u){
  return __builtin_bit_cast(half2v, u);
}

__device__ __forceinline__ float ftanh(float x){
  float e = __expf(2.f * x);
  return 1.f - 2.f * __builtin_amdgcn_rcpf(e + 1.f);
}

__device__ __forceinline__ float wave_sum64(float v){
  #pragma unroll
  for (int m = 32; m; m >>= 1) v += __shfl_xor(v, m);
  return v;
}
__device__ __forceinline__ float wave_max64(float v){
  #pragma unroll
  for (int m = 32; m; m >>= 1) v = fmaxf(v, __shfl_xor(v, m));
  return v;
}

// ---------------------------------------------------------------------------
// Kernel 1: per-(b,n) features -> hf (f16), s_i, s_j. 4 rows/block (4 waves).
// Blocks [384, 386): pack W_d into f16 fragments, q=(blk-384)*4+wave.
// ---------------------------------------------------------------------------
__global__ __launch_bounds__(256) void feat_kernel(
    const float* __restrict__ x_hist, const float* __restrict__ x_mark,
    const float* __restrict__ te_w1, const float* __restrict__ te_b1,
    const float* __restrict__ te_w2, const float* __restrict__ te_b2,
    const float* __restrict__ me_w1, const float* __restrict__ me_b1,
    const float* __restrict__ me_w2, const float* __restrict__ me_b2,
    const float* __restrict__ nf_w,  const float* __restrict__ nf_b,
    const float* __restrict__ ps_w1,
    _Float16* __restrict__ hf, float* __restrict__ si_out, float* __restrict__ sj_out,
    _Float16* __restrict__ wdf)
{
  const int tid  = threadIdx.x;
  const int lane = tid & 63;
  const int w    = tid >> 6;
  const int NB   = (B_ * N_) / 4;       // 384

  if (blockIdx.x >= NB) {               // W_d packing blocks
    const int q  = (blockIdx.x - NB) * 4 + w;   // 0..7 = nt*2+s
    const int nt = q >> 1, s = q & 1;
    const int col = (lane & 15) + 16 * nt;
    const int k0  = s * 32 + ((lane >> 4) << 3);
    #pragma unroll
    for (int jj = 0; jj < 8; ++jj) {
      float v = ps_w1[(2 * HID_ + k0 + jj) * HID_ + col];
      wdf[(q * 64 + lane) * 8 + jj] = (_Float16)v;
    }
    return;
  }

  const int row = blockIdx.x * 4 + w;   // b*N + n

  __shared__ float st [4][3];
  __shared__ float ms [4][FM_];
  __shared__ float t1s[4][TD_];
  __shared__ float m1s[4][MD_];
  __shared__ float hc [4][HID_];
  __shared__ float hs [4][HID_];

  const float* xh = x_hist + (long)row * T_;
  float s  = xh[lane];
  float mx = s;
  if (lane < T_ - 64) { float v = xh[lane + 64]; s += v; mx = fmaxf(mx, v); }
  s  = wave_sum64(s);
  mx = wave_max64(mx);
  if (lane == 0) { st[w][0] = xh[T_ - 1]; st[w][1] = s * (1.0f / T_); st[w][2] = mx; }

  const float* xm = x_mark + (long)row * T_ * FM_;
  float msv = 0.f;
  #pragma unroll
  for (int k = 0; k < 12; ++k) msv += xm[lane + 64 * k];
  msv += __shfl_xor(msv, 8);
  msv += __shfl_xor(msv, 16);
  msv += __shfl_xor(msv, 32);
  if (lane < FM_) ms[w][lane] = msv * (1.0f / T_);
  __syncthreads();

  if (lane < TD_) {
    float a = te_b1[lane];
    #pragma unroll
    for (int k = 0; k < 3; ++k) a += st[w][k] * te_w1[k * TD_ + lane];
    t1s[w][lane] = fmaxf(a, 0.f);
    float am = me_b1[lane];
    #pragma unroll
    for (int k = 0; k < FM_; ++k) am += ms[w][k] * me_w1[k * MD_ + lane];
    m1s[w][lane] = fmaxf(am, 0.f);
  }
  __syncthreads();
  if (lane < TD_) {
    float a = te_b2[lane];
    #pragma unroll
    for (int k = 0; k < TD_; ++k) a += t1s[w][k] * te_w2[k * TD_ + lane];
    hc[w][lane] = a;
    float am = me_b2[lane];
    #pragma unroll
    for (int k = 0; k < MD_; ++k) am += m1s[w][k] * me_w2[k * MD_ + lane];
    hc[w][TD_ + lane] = am;
  }
  __syncthreads();
  {
    float a = nf_b[lane];
    #pragma unroll
    for (int k = 0; k < HID_; ++k) a += hc[w][k] * nf_w[k * HID_ + lane];
    float hv = fmaxf(a, 0.f);
    hs[w][lane] = hv;
    hf[(long)row * HID_ + lane] = (_Float16)hv;
  }
  __syncthreads();
  {
    float a1 = 0.f, a2 = 0.f;
    #pragma unroll
    for (int k = 0; k < HID_; ++k) {
      float hv = hs[w][k];
      a1 += hv * ps_w1[k * HID_ + lane];
      a2 += hv * ps_w1[(HID_ + k) * HID_ + lane];
    }
    si_out[(long)row * HID_ + lane] = a1;
    sj_out[(long)row * HID_ + lane] = a2;
  }
}

// ---------------------------------------------------------------------------
// Kernel 2: pairwise delta via transposed f16 MFMA (E = Wd^T @ diff^T).
// Grid = PERB (600): block handles the SAME (a,tJ) tile for batch 0 then
// batch 1 (serial restage). 8 waves (512 thr); wave w owns i-rows 4w..4w+3.
// All 600 blocks co-resident (4 blocks/CU capacity) -> no tail generation.
// ---------------------------------------------------------------------------
__global__ __launch_bounds__(512, 8) void pair_kernel(
    const _Float16* __restrict__ hf, const float* __restrict__ si, const float* __restrict__ sj,
    const float* __restrict__ ps_b1, const float* __restrict__ ps_w2,
    const float* __restrict__ ps_b2, const _Float16* __restrict__ wdf,
    float* __restrict__ delta)
{
  int t = blockIdx.x;
  int a = 0;
  while (t >= NTILES - 2 * a) { t -= NTILES - 2 * a; ++a; }
  int tJ = 2 * a + t;
  const int i0 = a * TI32, j0 = tJ * TILE;

  __shared__ _Float16 hI[TI32][HID_];      // 4 KB (uniform-row reads)
  __shared__ _Float16 hJ[TILE][72];        // 2.25 KB (padded rows)
  __shared__ unsigned int PI[TI32][HID_];  // 8 KB  {sII+b1, sJI} f16x2
  __shared__ unsigned int PJ[TILE][68];    // 4.25 KB {sJJ, sIJ+b1} f16x2
  __shared__ unsigned int w2p[HID_];       // 256 B {w2,w2} f16x2

  const int tid  = threadIdx.x;
  const int lane = tid & 63;
  const int w    = tid >> 6;               // 0..7
  const int g    = lane >> 4;              // 0..3
  const int c16  = lane & 15;              // = j within tile
  const float b2 = ps_b2[0];

  // tile-invariant: Wd fragments (A operand) + w2 packing
  half8v wfr[8];
  const half8v* wdp = (const half8v*)wdf;
  #pragma unroll
  for (int q = 0; q < 8; ++q) wfr[q] = wdp[q * 64 + lane];
  if (tid >= 384 && tid < 400) {
    const int t4 = tid - 384;
    f32x4 wv = *(const f32x4*)(ps_w2 + t4 * 4);
    #pragma unroll
    for (int q = 0; q < 4; ++q) w2p[t4 * 4 + q] = pkrtz(wv[q], wv[q]);
  }

  const half2v hz = (half2v){(_Float16)0.f, (_Float16)0.f};

  for (int b = 0; b < B_; ++b) {
    // ---- staging for batch b (512 threads) ----
    if (tid < 256) {                         // I-side: 32 rows x 8 chunks
      const int r8 = tid >> 3;
      const int c0 = 8 * (tid & 7);
      const f32x4 bA = *(const f32x4*)(ps_b1 + c0);
      const f32x4 bB = *(const f32x4*)(ps_b1 + c0 + 4);
      const long gri = ((long)(b * N_) + i0 + r8) * HID_ + c0;
      *(half8v*)&hI[r8][c0] = *(const half8v*)(hf + gri);
      f32x4 ia = *(const f32x4*)(si + gri), ib = *(const f32x4*)(si + gri + 4);
      f32x4 ja = *(const f32x4*)(sj + gri), jb = *(const f32x4*)(sj + gri + 4);
      uint4v pa, pb;
      #pragma unroll
      for (int q = 0; q < 4; ++q) {
        pa[q] = pkrtz(ia[q] + bA[q], ja[q]);
        pb[q] = pkrtz(ib[q] + bB[q], jb[q]);
      }
      *(uint4v*)&PI[r8][c0] = pa;
      *(uint4v*)&PI[r8][c0 + 4] = pb;
    } else if (tid < 384) {                  // J-side: 16 rows x 8 chunks
      const int t2 = tid - 256;
      const int rj = t2 >> 3;
      const int c0 = 8 * (t2 & 7);
      const f32x4 bA = *(const f32x4*)(ps_b1 + c0);
      const f32x4 bB = *(const f32x4*)(ps_b1 + c0 + 4);
      const long grj = ((long)(b * N_) + j0 + rj) * HID_ + c0;
      *(half8v*)&hJ[rj][c0] = *(const half8v*)(hf + grj);
      f32x4 sja = *(const f32x4*)(sj + grj), sjb = *(const f32x4*)(sj + grj + 4);
      f32x4 sia = *(const f32x4*)(si + grj), sib = *(const f32x4*)(si + grj + 4);
      uint4v qa, qb;
      #pragma unroll
      for (int q = 0; q < 4; ++q) {
        qa[q] = pkrtz(sja[q], sia[q] + bA[q]);
        qb[q] = pkrtz(sjb[q], sib[q] + bB[q]);
      }
      *(uint4v*)&PJ[rj][c0] = qa;
      *(uint4v*)&PJ[rj][c0 + 4] = qb;
    }
    __syncthreads();

    // per-tile hoists
    half8v hj0 = *(const half8v*)&hJ[c16][8 * g];
    half8v hj1 = *(const half8v*)&hJ[c16][32 + 8 * g];
    uint4v pjh[4], w2h[4];
    #pragma unroll
    for (int mt = 0; mt < 4; ++mt) {
      pjh[mt] = *(const uint4v*)&PJ[c16][16 * mt + 4 * g];
      w2h[mt] = *(const uint4v*)&w2p[16 * mt + 4 * g];
    }

    float* drow = delta + (long)b * N_ * N_;

    #pragma unroll
    for (int m = 0; m < 4; ++m) {
      const int iloc = w * 4 + m;            // 8 waves x 4 rows = 32
      const int i = i0 + iloc;

      // diff = |hi - hj| in f16 (pk_sub + and-mask abs)
      half8v hi0 = *(const half8v*)&hI[iloc][8 * g];
      half8v hi1 = *(const half8v*)&hI[iloc][32 + 8 * g];
      half8v d0 = hi0 - hj0;
      half8v d1 = hi1 - hj1;
      uint4v u0 = __builtin_bit_cast(uint4v, d0) & 0x7FFF7FFFu;
      uint4v u1 = __builtin_bit_cast(uint4v, d1) & 0x7FFF7FFFu;
      half8v af0 = __builtin_bit_cast(half8v, u0);
      half8v af1 = __builtin_bit_cast(half8v, u1);

      f32x4 acc[4];
      #pragma unroll
      for (int mt = 0; mt < 4; ++mt) acc[mt] = (f32x4){0.f, 0.f, 0.f, 0.f};
      #pragma unroll
      for (int mt = 0; mt < 4; ++mt) {
        acc[mt] = __builtin_amdgcn_mfma_f32_16x16x32_f16(wfr[2 * mt + 0], af0, acc[mt], 0, 0, 0);
        acc[mt] = __builtin_amdgcn_mfma_f32_16x16x32_f16(wfr[2 * mt + 1], af1, acc[mt], 0, 0, 0);
      }

      // packed-f16 epilogue, two accumulator chains
      half2v sA = hz, sB = hz;
      #pragma unroll
      for (int mt = 0; mt < 4; ++mt) {
        uint4v pim = *(const uint4v*)&PI[iloc][16 * mt + 4 * g];   // uniform row
        #pragma unroll
        for (int r = 0; r < 4; ++r) {
          half2v pre = u2h(pim[r]) + u2h(pjh[mt][r]);
          auto avt = __builtin_amdgcn_cvt_pkrtz(acc[mt][r], acc[mt][r]);
          half2v av2;
          __builtin_memcpy(&av2, &avt, 4);
          pre = pre + av2;
          pre = __builtin_elementwise_max(pre, hz);
          if (mt & 1) sB = sB + pre * u2h(w2h[mt][r]);
          else        sA = sA + pre * u2h(w2h[mt][r]);
        }
      }
      half2v sP = sA + sB;
      {
        int v0 = __builtin_bit_cast(int, sP);
        int o0 = __shfl_xor(v0, 16);
        sP = sP + __builtin_bit_cast(half2v, o0);
        int v1 = __builtin_bit_cast(int, sP);
        int o1 = __shfl_xor(v1, 32);
        sP = sP + __builtin_bit_cast(half2v, o1);
      }

      if (g == 0) {
        const int j = j0 + c16;
        if (i < j) {
          float a1 = (float)sP[0] + b2;
          float a2 = (float)sP[1] + b2;
          float sym = 0.5f * (ftanh(a1) + ftanh(a2));
          drow[(long)i * N_ + j] = sym;
          drow[(long)j * N_ + i] = sym;
        } else if (i == j) {
          drow[(long)i * N_ + i] = 0.f;
        }
      }
    }
    __syncthreads();   // all readers done before next batch restages LDS
  }
}

// ---------------------------------------------------------------------------
// Kernel 3: a_hybrid = relu(a_static + lam*delta) row-normalized, in place.
// ---------------------------------------------------------------------------
__global__ __launch_bounds__(256) void norm_kernel(
    const float* __restrict__ a_static, const float* __restrict__ raw_lambda,
    float* __restrict__ out)
{
  const int row = blockIdx.x;           // b*N + i
  const int i   = row % N_;
  const int tid = threadIdx.x;
  const float lam = 1.f / (1.f + expf(-raw_lambda[0]));

  const float* arow = a_static + (long)i * N_;
  float* drow = out + (long)row * N_;

  float vals[3];
  float s = 0.f;
  #pragma unroll
  for (int r = 0; r < 3; ++r) {
    int j = r * 256 + tid;
    float v = arow[j] + lam * drow[j];
    v = fmaxf(v, 0.f);
    vals[r] = v;
    s += v;
  }
  s = wave_sum64(s);
  __shared__ float ps[4];
  if ((tid & 63) == 0) ps[tid >> 6] = s;
  __syncthreads();
  float tot = ps[0] + ps[1] + ps[2] + ps[3];
  float inv = 1.f / fmaxf(tot, 1e-6f);
  #pragma unroll
  for (int r = 0; r < 3; ++r) {
    int j = r * 256 + tid;
    drow[j] = vals[r] * inv;
  }
  if (row == 0 && tid == 0) out[(long)B_ * N_ * N_] = lam;
}

// ---------------------------------------------------------------------------
extern "C" void kernel_launch(void* const* d_in, const int* in_sizes, int n_in,
                              void* d_out, int out_size, void* d_ws, size_t ws_size,
                              hipStream_t stream) {
  const float* x_hist     = (const float*)d_in[0];
  const float* x_mark     = (const float*)d_in[1];
  const float* a_static   = (const float*)d_in[2];
  const float* te_w1      = (const float*)d_in[3];
  const float* te_b1      = (const float*)d_in[4];
  const float* te_w2      = (const float*)d_in[5];
  const float* te_b2      = (const float*)d_in[6];
  const float* me_w1      = (const float*)d_in[7];
  const float* me_b1      = (const float*)d_in[8];
  const float* me_w2      = (const float*)d_in[9];
  const float* me_b2      = (const float*)d_in[10];
  const float* nf_w       = (const float*)d_in[11];
  const float* nf_b       = (const float*)d_in[12];
  const float* ps_w1      = (const float*)d_in[13];
  const float* ps_b1      = (const float*)d_in[14];
  const float* ps_w2      = (const float*)d_in[15];
  const float* ps_b2      = (const float*)d_in[16];
  const float* raw_lambda = (const float*)d_in[17];

  float* out = (float*)d_out;
  char* ws = (char*)d_ws;
  _Float16* hf = (_Float16*)ws;                          // 196608 B
  float* si    = (float*)(ws + 196608);                  // 393216 B
  float* sj    = (float*)(ws + 196608 + 393216);         // 393216 B
  _Float16* wdf = (_Float16*)(ws + 196608 + 2 * 393216); // 8192 B

  feat_kernel<<<(B_ * N_) / 4 + 2, 256, 0, stream>>>(
      x_hist, x_mark, te_w1, te_b1, te_w2, te_b2,
      me_w1, me_b1, me_w2, me_b2, nf_w, nf_b, ps_w1, hf, si, sj, wdf);

  pair_kernel<<<PERB, 512, 0, stream>>>(
      hf, si, sj, ps_b1, ps_w2, ps_b2, wdf, out);

  norm_kernel<<<B_ * N_, 256, 0, stream>>>(a_static, raw_lambda, out);
}

// Round 17
// 37.653 us; speedup vs baseline: 5.2030x; 2.9577x over previous
//
#include <hip/hip_runtime.h>
#include <hip/hip_bf16.h>
#include <math.h>

#define B_ 2
#define N_ 768
#define T_ 96
#define FM_ 8
#define HID_ 64
#define TD_ 32
#define MD_ 32
#define TILE 16
#define TI32 32
#define NTILES (N_/TILE)            // 48
#define PERB 600                    // sum_{a=0}^{23} (48-2a)

typedef __attribute__((ext_vector_type(8))) _Float16 half8v;
typedef __attribute__((ext_vector_type(2))) _Float16 half2v;
typedef __attribute__((ext_vector_type(4))) float f32x4;
typedef __attribute__((ext_vector_type(4))) unsigned int uint4v;

__device__ __forceinline__ unsigned int pkrtz(float a, float b){
  auto t = __builtin_amdgcn_cvt_pkrtz(a, b);
  unsigned int u;
  __builtin_memcpy(&u, &t, 4);
  return u;
}
__device__ __forceinline__ half2v u2h(unsigned int u){
  return __builtin_bit_cast(half2v, u);
}

__device__ __forceinline__ float ftanh(float x){
  float e = __expf(2.f * x);
  return 1.f - 2.f * __builtin_amdgcn_rcpf(e + 1.f);
}

__device__ __forceinline__ float wave_sum64(float v){
  #pragma unroll
  for (int m = 32; m; m >>= 1) v += __shfl_xor(v, m);
  return v;
}
__device__ __forceinline__ float wave_max64(float v){
  #pragma unroll
  for (int m = 32; m; m >>= 1) v = fmaxf(v, __shfl_xor(v, m));
  return v;
}

// ---------------------------------------------------------------------------
// Kernel 1: per-(b,n) features -> hf (f16), s_i, s_j. 4 rows/block (4 waves).
// Blocks [384, 386): pack W_d into f16 fragments, q=(blk-384)*4+wave.
// ---------------------------------------------------------------------------
__global__ __launch_bounds__(256) void feat_kernel(
    const float* __restrict__ x_hist, const float* __restrict__ x_mark,
    const float* __restrict__ te_w1, const float* __restrict__ te_b1,
    const float* __restrict__ te_w2, const float* __restrict__ te_b2,
    const float* __restrict__ me_w1, const float* __restrict__ me_b1,
    const float* __restrict__ me_w2, const float* __restrict__ me_b2,
    const float* __restrict__ nf_w,  const float* __restrict__ nf_b,
    const float* __restrict__ ps_w1,
    _Float16* __restrict__ hf, float* __restrict__ si_out, float* __restrict__ sj_out,
    _Float16* __restrict__ wdf)
{
  const int tid  = threadIdx.x;
  const int lane = tid & 63;
  const int w    = tid >> 6;
  const int NB   = (B_ * N_) / 4;       // 384

  if (blockIdx.x >= NB) {               // W_d packing blocks
    const int q  = (blockIdx.x - NB) * 4 + w;   // 0..7 = nt*2+s
    const int nt = q >> 1, s = q & 1;
    const int col = (lane & 15) + 16 * nt;
    const int k0  = s * 32 + ((lane >> 4) << 3);
    #pragma unroll
    for (int jj = 0; jj < 8; ++jj) {
      float v = ps_w1[(2 * HID_ + k0 + jj) * HID_ + col];
      wdf[(q * 64 + lane) * 8 + jj] = (_Float16)v;
    }
    return;
  }

  const int row = blockIdx.x * 4 + w;   // b*N + n

  __shared__ float st [4][3];
  __shared__ float ms [4][FM_];
  __shared__ float t1s[4][TD_];
  __shared__ float m1s[4][MD_];
  __shared__ float hc [4][HID_];
  __shared__ float hs [4][HID_];

  const float* xh = x_hist + (long)row * T_;
  float s  = xh[lane];
  float mx = s;
  if (lane < T_ - 64) { float v = xh[lane + 64]; s += v; mx = fmaxf(mx, v); }
  s  = wave_sum64(s);
  mx = wave_max64(mx);
  if (lane == 0) { st[w][0] = xh[T_ - 1]; st[w][1] = s * (1.0f / T_); st[w][2] = mx; }

  const float* xm = x_mark + (long)row * T_ * FM_;
  float msv = 0.f;
  #pragma unroll
  for (int k = 0; k < 12; ++k) msv += xm[lane + 64 * k];
  msv += __shfl_xor(msv, 8);
  msv += __shfl_xor(msv, 16);
  msv += __shfl_xor(msv, 32);
  if (lane < FM_) ms[w][lane] = msv * (1.0f / T_);
  __syncthreads();

  if (lane < TD_) {
    float a = te_b1[lane];
    #pragma unroll
    for (int k = 0; k < 3; ++k) a += st[w][k] * te_w1[k * TD_ + lane];
    t1s[w][lane] = fmaxf(a, 0.f);
    float am = me_b1[lane];
    #pragma unroll
    for (int k = 0; k < FM_; ++k) am += ms[w][k] * me_w1[k * MD_ + lane];
    m1s[w][lane] = fmaxf(am, 0.f);
  }
  __syncthreads();
  if (lane < TD_) {
    float a = te_b2[lane];
    #pragma unroll
    for (int k = 0; k < TD_; ++k) a += t1s[w][k] * te_w2[k * TD_ + lane];
    hc[w][lane] = a;
    float am = me_b2[lane];
    #pragma unroll
    for (int k = 0; k < MD_; ++k) am += m1s[w][k] * me_w2[k * MD_ + lane];
    hc[w][TD_ + lane] = am;
  }
  __syncthreads();
  {
    float a = nf_b[lane];
    #pragma unroll
    for (int k = 0; k < HID_; ++k) a += hc[w][k] * nf_w[k * HID_ + lane];
    float hv = fmaxf(a, 0.f);
    hs[w][lane] = hv;
    hf[(long)row * HID_ + lane] = (_Float16)hv;
  }
  __syncthreads();
  {
    float a1 = 0.f, a2 = 0.f;
    #pragma unroll
    for (int k = 0; k < HID_; ++k) {
      float hv = hs[w][k];
      a1 += hv * ps_w1[k * HID_ + lane];
      a2 += hv * ps_w1[(HID_ + k) * HID_ + lane];
    }
    si_out[(long)row * HID_ + lane] = a1;
    sj_out[(long)row * HID_ + lane] = a2;
  }
}

// ---------------------------------------------------------------------------
// Kernel 2: pairwise delta via transposed f16 MFMA (E = Wd^T @ diff^T).
// Grid = PERB (600): block handles the SAME (a,tJ) tile for batch 0 then
// batch 1 (serial restage). 8 waves (512 thr); wave w owns i-rows 4w..4w+3.
// NOTE: plain __launch_bounds__(512) — the (512,8) variant capped VGPR at 32
// and spilled everything to scratch (R16: FETCH 7MB->192MB, 3x slower).
// ---------------------------------------------------------------------------
__global__ __launch_bounds__(512) void pair_kernel(
    const _Float16* __restrict__ hf, const float* __restrict__ si, const float* __restrict__ sj,
    const float* __restrict__ ps_b1, const float* __restrict__ ps_w2,
    const float* __restrict__ ps_b2, const _Float16* __restrict__ wdf,
    float* __restrict__ delta)
{
  int t = blockIdx.x;
  int a = 0;
  while (t >= NTILES - 2 * a) { t -= NTILES - 2 * a; ++a; }
  int tJ = 2 * a + t;
  const int i0 = a * TI32, j0 = tJ * TILE;

  __shared__ _Float16 hI[TI32][HID_];      // 4 KB (uniform-row reads)
  __shared__ _Float16 hJ[TILE][72];        // 2.25 KB (padded rows)
  __shared__ unsigned int PI[TI32][HID_];  // 8 KB  {sII+b1, sJI} f16x2
  __shared__ unsigned int PJ[TILE][68];    // 4.25 KB {sJJ, sIJ+b1} f16x2
  __shared__ unsigned int w2p[HID_];       // 256 B {w2,w2} f16x2

  const int tid  = threadIdx.x;
  const int lane = tid & 63;
  const int w    = tid >> 6;               // 0..7
  const int g    = lane >> 4;              // 0..3
  const int c16  = lane & 15;              // = j within tile
  const float b2 = ps_b2[0];

  // tile-invariant: Wd fragments (A operand) + w2 packing
  half8v wfr[8];
  const half8v* wdp = (const half8v*)wdf;
  #pragma unroll
  for (int q = 0; q < 8; ++q) wfr[q] = wdp[q * 64 + lane];
  if (tid >= 384 && tid < 400) {
    const int t4 = tid - 384;
    f32x4 wv = *(const f32x4*)(ps_w2 + t4 * 4);
    #pragma unroll
    for (int q = 0; q < 4; ++q) w2p[t4 * 4 + q] = pkrtz(wv[q], wv[q]);
  }

  const half2v hz = (half2v){(_Float16)0.f, (_Float16)0.f};

  for (int b = 0; b < B_; ++b) {
    // ---- staging for batch b (512 threads) ----
    if (tid < 256) {                         // I-side: 32 rows x 8 chunks
      const int r8 = tid >> 3;
      const int c0 = 8 * (tid & 7);
      const f32x4 bA = *(const f32x4*)(ps_b1 + c0);
      const f32x4 bB = *(const f32x4*)(ps_b1 + c0 + 4);
      const long gri = ((long)(b * N_) + i0 + r8) * HID_ + c0;
      *(half8v*)&hI[r8][c0] = *(const half8v*)(hf + gri);
      f32x4 ia = *(const f32x4*)(si + gri), ib = *(const f32x4*)(si + gri + 4);
      f32x4 ja = *(const f32x4*)(sj + gri), jb = *(const f32x4*)(sj + gri + 4);
      uint4v pa, pb;
      #pragma unroll
      for (int q = 0; q < 4; ++q) {
        pa[q] = pkrtz(ia[q] + bA[q], ja[q]);
        pb[q] = pkrtz(ib[q] + bB[q], jb[q]);
      }
      *(uint4v*)&PI[r8][c0] = pa;
      *(uint4v*)&PI[r8][c0 + 4] = pb;
    } else if (tid < 384) {                  // J-side: 16 rows x 8 chunks
      const int t2 = tid - 256;
      const int rj = t2 >> 3;
      const int c0 = 8 * (t2 & 7);
      const f32x4 bA = *(const f32x4*)(ps_b1 + c0);
      const f32x4 bB = *(const f32x4*)(ps_b1 + c0 + 4);
      const long grj = ((long)(b * N_) + j0 + rj) * HID_ + c0;
      *(half8v*)&hJ[rj][c0] = *(const half8v*)(hf + grj);
      f32x4 sja = *(const f32x4*)(sj + grj), sjb = *(const f32x4*)(sj + grj + 4);
      f32x4 sia = *(const f32x4*)(si + grj), sib = *(const f32x4*)(si + grj + 4);
      uint4v qa, qb;
      #pragma unroll
      for (int q = 0; q < 4; ++q) {
        qa[q] = pkrtz(sja[q], sia[q] + bA[q]);
        qb[q] = pkrtz(sjb[q], sib[q] + bB[q]);
      }
      *(uint4v*)&PJ[rj][c0] = qa;
      *(uint4v*)&PJ[rj][c0 + 4] = qb;
    }
    __syncthreads();

    // per-tile hoists
    half8v hj0 = *(const half8v*)&hJ[c16][8 * g];
    half8v hj1 = *(const half8v*)&hJ[c16][32 + 8 * g];
    uint4v pjh[4], w2h[4];
    #pragma unroll
    for (int mt = 0; mt < 4; ++mt) {
      pjh[mt] = *(const uint4v*)&PJ[c16][16 * mt + 4 * g];
      w2h[mt] = *(const uint4v*)&w2p[16 * mt + 4 * g];
    }

    float* drow = delta + (long)b * N_ * N_;

    #pragma unroll
    for (int m = 0; m < 4; ++m) {
      const int iloc = w * 4 + m;            // 8 waves x 4 rows = 32
      const int i = i0 + iloc;

      // diff = |hi - hj| in f16 (pk_sub + and-mask abs)
      half8v hi0 = *(const half8v*)&hI[iloc][8 * g];
      half8v hi1 = *(const half8v*)&hI[iloc][32 + 8 * g];
      half8v d0 = hi0 - hj0;
      half8v d1 = hi1 - hj1;
      uint4v u0 = __builtin_bit_cast(uint4v, d0) & 0x7FFF7FFFu;
      uint4v u1 = __builtin_bit_cast(uint4v, d1) & 0x7FFF7FFFu;
      half8v af0 = __builtin_bit_cast(half8v, u0);
      half8v af1 = __builtin_bit_cast(half8v, u1);

      f32x4 acc[4];
      #pragma unroll
      for (int mt = 0; mt < 4; ++mt) acc[mt] = (f32x4){0.f, 0.f, 0.f, 0.f};
      #pragma unroll
      for (int mt = 0; mt < 4; ++mt) {
        acc[mt] = __builtin_amdgcn_mfma_f32_16x16x32_f16(wfr[2 * mt + 0], af0, acc[mt], 0, 0, 0);
        acc[mt] = __builtin_amdgcn_mfma_f32_16x16x32_f16(wfr[2 * mt + 1], af1, acc[mt], 0, 0, 0);
      }

      // packed-f16 epilogue, two accumulator chains
      half2v sA = hz, sB = hz;
      #pragma unroll
      for (int mt = 0; mt < 4; ++mt) {
        uint4v pim = *(const uint4v*)&PI[iloc][16 * mt + 4 * g];   // uniform row
        #pragma unroll
        for (int r = 0; r < 4; ++r) {
          half2v pre = u2h(pim[r]) + u2h(pjh[mt][r]);
          auto avt = __builtin_amdgcn_cvt_pkrtz(acc[mt][r], acc[mt][r]);
          half2v av2;
          __builtin_memcpy(&av2, &avt, 4);
          pre = pre + av2;
          pre = __builtin_elementwise_max(pre, hz);
          if (mt & 1) sB = sB + pre * u2h(w2h[mt][r]);
          else        sA = sA + pre * u2h(w2h[mt][r]);
        }
      }
      half2v sP = sA + sB;
      {
        int v0 = __builtin_bit_cast(int, sP);
        int o0 = __shfl_xor(v0, 16);
        sP = sP + __builtin_bit_cast(half2v, o0);
        int v1 = __builtin_bit_cast(int, sP);
        int o1 = __shfl_xor(v1, 32);
        sP = sP + __builtin_bit_cast(half2v, o1);
      }

      if (g == 0) {
        const int j = j0 + c16;
        if (i < j) {
          float a1 = (float)sP[0] + b2;
          float a2 = (float)sP[1] + b2;
          float sym = 0.5f * (ftanh(a1) + ftanh(a2));
          drow[(long)i * N_ + j] = sym;
          drow[(long)j * N_ + i] = sym;
        } else if (i == j) {
          drow[(long)i * N_ + i] = 0.f;
        }
      }
    }
    __syncthreads();   // all readers done before next batch restages LDS
  }
}

// ---------------------------------------------------------------------------
// Kernel 3: a_hybrid = relu(a_static + lam*delta) row-normalized, in place.
// ---------------------------------------------------------------------------
__global__ __launch_bounds__(256) void norm_kernel(
    const float* __restrict__ a_static, const float* __restrict__ raw_lambda,
    float* __restrict__ out)
{
  const int row = blockIdx.x;           // b*N + i
  const int i   = row % N_;
  const int tid = threadIdx.x;
  const float lam = 1.f / (1.f + expf(-raw_lambda[0]));

  const float* arow = a_static + (long)i * N_;
  float* drow = out + (long)row * N_;

  float vals[3];
  float s = 0.f;
  #pragma unroll
  for (int r = 0; r < 3; ++r) {
    int j = r * 256 + tid;
    float v = arow[j] + lam * drow[j];
    v = fmaxf(v, 0.f);
    vals[r] = v;
    s += v;
  }
  s = wave_sum64(s);
  __shared__ float ps[4];
  if ((tid & 63) == 0) ps[tid >> 6] = s;
  __syncthreads();
  float tot = ps[0] + ps[1] + ps[2] + ps[3];
  float inv = 1.f / fmaxf(tot, 1e-6f);
  #pragma unroll
  for (int r = 0; r < 3; ++r) {
    int j = r * 256 + tid;
    drow[j] = vals[r] * inv;
  }
  if (row == 0 && tid == 0) out[(long)B_ * N_ * N_] = lam;
}

// ---------------------------------------------------------------------------
extern "C" void kernel_launch(void* const* d_in, const int* in_sizes, int n_in,
                              void* d_out, int out_size, void* d_ws, size_t ws_size,
                              hipStream_t stream) {
  const float* x_hist     = (const float*)d_in[0];
  const float* x_mark     = (const float*)d_in[1];
  const float* a_static   = (const float*)d_in[2];
  const float* te_w1      = (const float*)d_in[3];
  const float* te_b1      = (const float*)d_in[4];
  const float* te_w2      = (const float*)d_in[5];
  const float* te_b2      = (const float*)d_in[6];
  const float* me_w1      = (const float*)d_in[7];
  const float* me_b1      = (const float*)d_in[8];
  const float* me_w2      = (const float*)d_in[9];
  const float* me_b2      = (const float*)d_in[10];
  const float* nf_w       = (const float*)d_in[11];
  const float* nf_b       = (const float*)d_in[12];
  const float* ps_w1      = (const float*)d_in[13];
  const float* ps_b1      = (const float*)d_in[14];
  const float* ps_w2      = (const float*)d_in[15];
  const float* ps_b2      = (const float*)d_in[16];
  const float* raw_lambda = (const float*)d_in[17];

  float* out = (float*)d_out;
  char* ws = (char*)d_ws;
  _Float16* hf = (_Float16*)ws;                          // 196608 B
  float* si    = (float*)(ws + 196608);                  // 393216 B
  float* sj    = (float*)(ws + 196608 + 393216);         // 393216 B
  _Float16* wdf = (_Float16*)(ws + 196608 + 2 * 393216); // 8192 B

  feat_kernel<<<(B_ * N_) / 4 + 2, 256, 0, stream>>>(
      x_hist, x_mark, te_w1, te_b1, te_w2, te_b2,
      me_w1, me_b1, me_w2, me_b2, nf_w, nf_b, ps_w1, hf, si, sj, wdf);

  pair_kernel<<<PERB, 512, 0, stream>>>(
      hf, si, sj, ps_b1, ps_w2, ps_b2, wdf, out);

  norm_kernel<<<B_ * N_, 256, 0, stream>>>(a_static, raw_lambda, out);
}

// Round 18
// 33.142 us; speedup vs baseline: 5.9111x; 1.1361x over previous
//
#include <hip/hip_runtime.h>
#include <hip/hip_bf16.h>
#include <math.h>

#define B_ 2
#define N_ 768
#define T_ 96
#define FM_ 8
#define HID_ 64
#define TD_ 32
#define MD_ 32
#define TILE 16
#define TI32 32
#define NTILES (N_/TILE)            // 48
#define PERB 600                    // sum_{a=0}^{23} (48-2a)

typedef __attribute__((ext_vector_type(8))) _Float16 half8v;
typedef __attribute__((ext_vector_type(2))) _Float16 half2v;
typedef __attribute__((ext_vector_type(4))) float f32x4;
typedef __attribute__((ext_vector_type(4))) unsigned int uint4v;

__device__ __forceinline__ unsigned int pkrtz(float a, float b){
  auto t = __builtin_amdgcn_cvt_pkrtz(a, b);
  unsigned int u;
  __builtin_memcpy(&u, &t, 4);
  return u;
}
__device__ __forceinline__ half2v u2h(unsigned int u){
  return __builtin_bit_cast(half2v, u);
}

__device__ __forceinline__ float ftanh(float x){
  float e = __expf(2.f * x);
  return 1.f - 2.f * __builtin_amdgcn_rcpf(e + 1.f);
}

__device__ __forceinline__ float wave_sum64(float v){
  #pragma unroll
  for (int m = 32; m; m >>= 1) v += __shfl_xor(v, m);
  return v;
}
__device__ __forceinline__ float wave_max64(float v){
  #pragma unroll
  for (int m = 32; m; m >>= 1) v = fmaxf(v, __shfl_xor(v, m));
  return v;
}

// ---------------------------------------------------------------------------
// Kernel 1: per-(b,n) features -> hf (f16), s_i, s_j. 4 rows/block (4 waves).
// Blocks [384, 386): pack W_d into f16 fragments, q=(blk-384)*4+wave.
// ---------------------------------------------------------------------------
__global__ __launch_bounds__(256) void feat_kernel(
    const float* __restrict__ x_hist, const float* __restrict__ x_mark,
    const float* __restrict__ te_w1, const float* __restrict__ te_b1,
    const float* __restrict__ te_w2, const float* __restrict__ te_b2,
    const float* __restrict__ me_w1, const float* __restrict__ me_b1,
    const float* __restrict__ me_w2, const float* __restrict__ me_b2,
    const float* __restrict__ nf_w,  const float* __restrict__ nf_b,
    const float* __restrict__ ps_w1,
    _Float16* __restrict__ hf, float* __restrict__ si_out, float* __restrict__ sj_out,
    _Float16* __restrict__ wdf)
{
  const int tid  = threadIdx.x;
  const int lane = tid & 63;
  const int w    = tid >> 6;
  const int NB   = (B_ * N_) / 4;       // 384

  if (blockIdx.x >= NB) {               // W_d packing blocks
    const int q  = (blockIdx.x - NB) * 4 + w;   // 0..7 = nt*2+s
    const int nt = q >> 1, s = q & 1;
    const int col = (lane & 15) + 16 * nt;
    const int k0  = s * 32 + ((lane >> 4) << 3);
    #pragma unroll
    for (int jj = 0; jj < 8; ++jj) {
      float v = ps_w1[(2 * HID_ + k0 + jj) * HID_ + col];
      wdf[(q * 64 + lane) * 8 + jj] = (_Float16)v;
    }
    return;
  }

  const int row = blockIdx.x * 4 + w;   // b*N + n

  __shared__ float st [4][3];
  __shared__ float ms [4][FM_];
  __shared__ float t1s[4][TD_];
  __shared__ float m1s[4][MD_];
  __shared__ float hc [4][HID_];
  __shared__ float hs [4][HID_];

  const float* xh = x_hist + (long)row * T_;
  float s  = xh[lane];
  float mx = s;
  if (lane < T_ - 64) { float v = xh[lane + 64]; s += v; mx = fmaxf(mx, v); }
  s  = wave_sum64(s);
  mx = wave_max64(mx);
  if (lane == 0) { st[w][0] = xh[T_ - 1]; st[w][1] = s * (1.0f / T_); st[w][2] = mx; }

  const float* xm = x_mark + (long)row * T_ * FM_;
  float msv = 0.f;
  #pragma unroll
  for (int k = 0; k < 12; ++k) msv += xm[lane + 64 * k];
  msv += __shfl_xor(msv, 8);
  msv += __shfl_xor(msv, 16);
  msv += __shfl_xor(msv, 32);
  if (lane < FM_) ms[w][lane] = msv * (1.0f / T_);
  __syncthreads();

  if (lane < TD_) {
    float a = te_b1[lane];
    #pragma unroll
    for (int k = 0; k < 3; ++k) a += st[w][k] * te_w1[k * TD_ + lane];
    t1s[w][lane] = fmaxf(a, 0.f);
    float am = me_b1[lane];
    #pragma unroll
    for (int k = 0; k < FM_; ++k) am += ms[w][k] * me_w1[k * MD_ + lane];
    m1s[w][lane] = fmaxf(am, 0.f);
  }
  __syncthreads();
  if (lane < TD_) {
    float a = te_b2[lane];
    #pragma unroll
    for (int k = 0; k < TD_; ++k) a += t1s[w][k] * te_w2[k * TD_ + lane];
    hc[w][lane] = a;
    float am = me_b2[lane];
    #pragma unroll
    for (int k = 0; k < MD_; ++k) am += m1s[w][k] * me_w2[k * MD_ + lane];
    hc[w][TD_ + lane] = am;
  }
  __syncthreads();
  {
    float a = nf_b[lane];
    #pragma unroll
    for (int k = 0; k < HID_; ++k) a += hc[w][k] * nf_w[k * HID_ + lane];
    float hv = fmaxf(a, 0.f);
    hs[w][lane] = hv;
    hf[(long)row * HID_ + lane] = (_Float16)hv;
  }
  __syncthreads();
  {
    float a1 = 0.f, a2 = 0.f;
    #pragma unroll
    for (int k = 0; k < HID_; ++k) {
      float hv = hs[w][k];
      a1 += hv * ps_w1[k * HID_ + lane];
      a2 += hv * ps_w1[(HID_ + k) * HID_ + lane];
    }
    si_out[(long)row * HID_ + lane] = a1;
    sj_out[(long)row * HID_ + lane] = a2;
  }
}

// ---------------------------------------------------------------------------
// Kernel 2: pairwise delta via transposed f16 MFMA (E = Wd^T @ diff^T).
// Block = 32 i-rows x 16 j-rows, 8 waves (512 thr); wave w owns i-rows
// 4w..4w+3. VGPR=60 (<64 cliff, m69) -> 4 blocks/CU resident.
// ---------------------------------------------------------------------------
__global__ __launch_bounds__(512) void pair_kernel(
    const _Float16* __restrict__ hf, const float* __restrict__ si, const float* __restrict__ sj,
    const float* __restrict__ ps_b1, const float* __restrict__ ps_w2,
    const float* __restrict__ ps_b2, const _Float16* __restrict__ wdf,
    float* __restrict__ delta)
{
  int bidx = blockIdx.x;
  int b = bidx / PERB;
  int t = bidx % PERB;
  int a = 0;
  while (t >= NTILES - 2 * a) { t -= NTILES - 2 * a; ++a; }
  int tJ = 2 * a + t;
  const int i0 = a * TI32, j0 = tJ * TILE;

  __shared__ _Float16 hI[TI32][HID_];      // 4 KB (uniform-row reads)
  __shared__ _Float16 hJ[TILE][72];        // 2.25 KB (padded rows)
  __shared__ unsigned int PI[TI32][HID_];  // 8 KB  {sII+b1, sJI} f16x2
  __shared__ unsigned int PJ[TILE][68];    // 4.25 KB {sJJ, sIJ+b1} f16x2
  __shared__ unsigned int w2p[HID_];       // 256 B {w2,w2} f16x2

  const int tid  = threadIdx.x;
  const int lane = tid & 63;
  const int w    = tid >> 6;               // 0..7

  // ---- staging (512 threads) ----
  if (tid < 256) {                         // I-side: 32 rows x 8 chunks
    const int r8 = tid >> 3;
    const int c0 = 8 * (tid & 7);
    const f32x4 bA = *(const f32x4*)(ps_b1 + c0);
    const f32x4 bB = *(const f32x4*)(ps_b1 + c0 + 4);
    const long gri = ((long)(b * N_) + i0 + r8) * HID_ + c0;
    *(half8v*)&hI[r8][c0] = *(const half8v*)(hf + gri);
    f32x4 ia = *(const f32x4*)(si + gri), ib = *(const f32x4*)(si + gri + 4);
    f32x4 ja = *(const f32x4*)(sj + gri), jb = *(const f32x4*)(sj + gri + 4);
    uint4v pa, pb;
    #pragma unroll
    for (int q = 0; q < 4; ++q) {
      pa[q] = pkrtz(ia[q] + bA[q], ja[q]);
      pb[q] = pkrtz(ib[q] + bB[q], jb[q]);
    }
    *(uint4v*)&PI[r8][c0] = pa;
    *(uint4v*)&PI[r8][c0 + 4] = pb;
  } else if (tid < 384) {                  // J-side: 16 rows x 8 chunks
    const int t2 = tid - 256;
    const int rj = t2 >> 3;
    const int c0 = 8 * (t2 & 7);
    const f32x4 bA = *(const f32x4*)(ps_b1 + c0);
    const f32x4 bB = *(const f32x4*)(ps_b1 + c0 + 4);
    const long grj = ((long)(b * N_) + j0 + rj) * HID_ + c0;
    *(half8v*)&hJ[rj][c0] = *(const half8v*)(hf + grj);
    f32x4 sja = *(const f32x4*)(sj + grj), sjb = *(const f32x4*)(sj + grj + 4);
    f32x4 sia = *(const f32x4*)(si + grj), sib = *(const f32x4*)(si + grj + 4);
    uint4v qa, qb;
    #pragma unroll
    for (int q = 0; q < 4; ++q) {
      qa[q] = pkrtz(sja[q], sia[q] + bA[q]);
      qb[q] = pkrtz(sjb[q], sib[q] + bB[q]);
    }
    *(uint4v*)&PJ[rj][c0] = qa;
    *(uint4v*)&PJ[rj][c0 + 4] = qb;
  } else if (tid < 400) {                  // w2: 16 threads x 4
    const int t4 = tid - 384;
    f32x4 wv = *(const f32x4*)(ps_w2 + t4 * 4);
    #pragma unroll
    for (int q = 0; q < 4; ++q) w2p[t4 * 4 + q] = pkrtz(wv[q], wv[q]);
  }
  const float b2 = ps_b2[0];
  __syncthreads();

  const int g   = lane >> 4;     // 0..3
  const int c16 = lane & 15;     // = j within tile

  // Wd fragments (A operand), prepacked f16
  half8v wfr[8];
  const half8v* wdp = (const half8v*)wdf;
  #pragma unroll
  for (int q = 0; q < 8; ++q) wfr[q] = wdp[q * 64 + lane];

  // m-invariant hoists
  half8v hj0 = *(const half8v*)&hJ[c16][8 * g];
  half8v hj1 = *(const half8v*)&hJ[c16][32 + 8 * g];
  uint4v pjh[4], w2h[4];
  #pragma unroll
  for (int mt = 0; mt < 4; ++mt) {
    pjh[mt] = *(const uint4v*)&PJ[c16][16 * mt + 4 * g];
    w2h[mt] = *(const uint4v*)&w2p[16 * mt + 4 * g];
  }
  const half2v hz = (half2v){(_Float16)0.f, (_Float16)0.f};

  float* drow = delta + (long)b * N_ * N_;

  #pragma unroll
  for (int m = 0; m < 4; ++m) {
    const int iloc = w * 4 + m;            // 8 waves x 4 rows = 32
    const int i = i0 + iloc;

    // diff = |hi - hj| in f16 (pk_sub + and-mask abs)
    half8v hi0 = *(const half8v*)&hI[iloc][8 * g];
    half8v hi1 = *(const half8v*)&hI[iloc][32 + 8 * g];
    half8v d0 = hi0 - hj0;
    half8v d1 = hi1 - hj1;
    uint4v u0 = __builtin_bit_cast(uint4v, d0) & 0x7FFF7FFFu;
    uint4v u1 = __builtin_bit_cast(uint4v, d1) & 0x7FFF7FFFu;
    half8v af0 = __builtin_bit_cast(half8v, u0);
    half8v af1 = __builtin_bit_cast(half8v, u1);

    f32x4 acc[4];
    #pragma unroll
    for (int mt = 0; mt < 4; ++mt) acc[mt] = (f32x4){0.f, 0.f, 0.f, 0.f};
    #pragma unroll
    for (int mt = 0; mt < 4; ++mt) {
      acc[mt] = __builtin_amdgcn_mfma_f32_16x16x32_f16(wfr[2 * mt + 0], af0, acc[mt], 0, 0, 0);
      acc[mt] = __builtin_amdgcn_mfma_f32_16x16x32_f16(wfr[2 * mt + 1], af1, acc[mt], 0, 0, 0);
    }

    // packed-f16 epilogue, two accumulator chains
    half2v sA = hz, sB = hz;
    #pragma unroll
    for (int mt = 0; mt < 4; ++mt) {
      uint4v pim = *(const uint4v*)&PI[iloc][16 * mt + 4 * g];   // uniform row
      #pragma unroll
      for (int r = 0; r < 4; ++r) {
        half2v pre = u2h(pim[r]) + u2h(pjh[mt][r]);
        auto avt = __builtin_amdgcn_cvt_pkrtz(acc[mt][r], acc[mt][r]);
        half2v av2;
        __builtin_memcpy(&av2, &avt, 4);
        pre = pre + av2;
        pre = __builtin_elementwise_max(pre, hz);
        if (mt & 1) sB = sB + pre * u2h(w2h[mt][r]);
        else        sA = sA + pre * u2h(w2h[mt][r]);
      }
    }
    half2v sP = sA + sB;
    {
      int v0 = __builtin_bit_cast(int, sP);
      int o0 = __shfl_xor(v0, 16);
      sP = sP + __builtin_bit_cast(half2v, o0);
      int v1 = __builtin_bit_cast(int, sP);
      int o1 = __shfl_xor(v1, 32);
      sP = sP + __builtin_bit_cast(half2v, o1);
    }

    if (g == 0) {
      const int j = j0 + c16;
      if (i < j) {
        float a1 = (float)sP[0] + b2;
        float a2 = (float)sP[1] + b2;
        float sym = 0.5f * (ftanh(a1) + ftanh(a2));
        drow[(long)i * N_ + j] = sym;
        drow[(long)j * N_ + i] = sym;
      } else if (i == j) {
        drow[(long)i * N_ + i] = 0.f;
      }
    }
  }
}

// ---------------------------------------------------------------------------
// Kernel 3: a_hybrid = relu(a_static + lam*delta) row-normalized, in place.
// ---------------------------------------------------------------------------
__global__ __launch_bounds__(256) void norm_kernel(
    const float* __restrict__ a_static, const float* __restrict__ raw_lambda,
    float* __restrict__ out)
{
  const int row = blockIdx.x;           // b*N + i
  const int i   = row % N_;
  const int tid = threadIdx.x;
  const float lam = 1.f / (1.f + expf(-raw_lambda[0]));

  const float* arow = a_static + (long)i * N_;
  float* drow = out + (long)row * N_;

  float vals[3];
  float s = 0.f;
  #pragma unroll
  for (int r = 0; r < 3; ++r) {
    int j = r * 256 + tid;
    float v = arow[j] + lam * drow[j];
    v = fmaxf(v, 0.f);
    vals[r] = v;
    s += v;
  }
  s = wave_sum64(s);
  __shared__ float ps[4];
  if ((tid & 63) == 0) ps[tid >> 6] = s;
  __syncthreads();
  float tot = ps[0] + ps[1] + ps[2] + ps[3];
  float inv = 1.f / fmaxf(tot, 1e-6f);
  #pragma unroll
  for (int r = 0; r < 3; ++r) {
    int j = r * 256 + tid;
    drow[j] = vals[r] * inv;
  }
  if (row == 0 && tid == 0) out[(long)B_ * N_ * N_] = lam;
}

// ---------------------------------------------------------------------------
extern "C" void kernel_launch(void* const* d_in, const int* in_sizes, int n_in,
                              void* d_out, int out_size, void* d_ws, size_t ws_size,
                              hipStream_t stream) {
  const float* x_hist     = (const float*)d_in[0];
  const float* x_mark     = (const float*)d_in[1];
  const float* a_static   = (const float*)d_in[2];
  const float* te_w1      = (const float*)d_in[3];
  const float* te_b1      = (const float*)d_in[4];
  const float* te_w2      = (const float*)d_in[5];
  const float* te_b2      = (const float*)d_in[6];
  const float* me_w1      = (const float*)d_in[7];
  const float* me_b1      = (const float*)d_in[8];
  const float* me_w2      = (const float*)d_in[9];
  const float* me_b2      = (const float*)d_in[10];
  const float* nf_w       = (const float*)d_in[11];
  const float* nf_b       = (const float*)d_in[12];
  const float* ps_w1      = (const float*)d_in[13];
  const float* ps_b1      = (const float*)d_in[14];
  const float* ps_w2      = (const float*)d_in[15];
  const float* ps_b2      = (const float*)d_in[16];
  const float* raw_lambda = (const float*)d_in[17];

  float* out = (float*)d_out;
  char* ws = (char*)d_ws;
  _Float16* hf = (_Float16*)ws;                          // 196608 B
  float* si    = (float*)(ws + 196608);                  // 393216 B
  float* sj    = (float*)(ws + 196608 + 393216);         // 393216 B
  _Float16* wdf = (_Float16*)(ws + 196608 + 2 * 393216); // 8192 B

  feat_kernel<<<(B_ * N_) / 4 + 2, 256, 0, stream>>>(
      x_hist, x_mark, te_w1, te_b1, te_w2, te_b2,
      me_w1, me_b1, me_w2, me_b2, nf_w, nf_b, ps_w1, hf, si, sj, wdf);

  pair_kernel<<<B_ * PERB, 512, 0, stream>>>(
      hf, si, sj, ps_b1, ps_w2, ps_b2, wdf, out);

  norm_kernel<<<B_ * N_, 256, 0, stream>>>(a_static, raw_lambda, out);
}